// Round 1
// 603.699 us; speedup vs baseline: 1.0123x; 1.0123x over previous
//
#include <hip/hip_runtime.h>

// MixedDimTableBatchedEmbeddingBags — table-phased persistent kernel.
// 8 tables, 250k rows, dims {16,32,64,128,16,32,64,128}, B=8192, L=32.
// out[b, cb_t + 4*cg + d] = sum_l weights[woff_t + idx[t,b,l]*dim_t + 4*cg + d] * psw[t,b,l]
//
// g' enumerates output float4-groups TABLE-MAJOR: (t, b, cg). A grid-stride
// loop over exactly 262,144 resident threads (1024 blocks x 256, 16 waves/CU,
// all co-resident) walks g' in 4 sweeps; each sweep's weight working set is
// <=128 MB (t0..t2+1/8 t3 | rest t3+t4 | t5+t6+1/4 t7 | rest t7) and fits the
// 256 MiB Infinity Cache, so repeat rows (~38% of lookups: 262k draws on 250k
// rows/table) become L3 hits instead of thrashing a 480 MB random range.

#define BATCH    8192
#define BAG_L    32
#define GROUPS_PER_ROW 120                      // 480 floats / 4
#define TOTAL_GROUPS (BATCH * GROUPS_PER_ROW)   // 983040
#define NBLOCKS  1024
#define NTHREADS 256
#define GRID_THREADS (NBLOCKS * NTHREADS)       // 262144 -> 4 sweeps

// per-table float4-group prefix:  G_t = B * dim_t/4
__constant__ unsigned c_pref[8] = {0u, 32768u, 98304u, 229376u,
                                   491520u, 524288u, 589824u, 720896u};
__constant__ int      c_s[8]    = {2, 3, 4, 5, 2, 3, 4, 5};   // log2(dim/4)
__constant__ int      c_cb[8]   = {0, 4, 12, 28, 60, 64, 72, 88};
__constant__ unsigned c_woff[8] = {0u, 4000000u, 12000000u, 28000000u,
                                   60000000u, 64000000u, 72000000u, 88000000u};

__global__ __launch_bounds__(NTHREADS, 4) void emb_bags_kernel(
    const float* __restrict__ weights,
    const int*   __restrict__ indices,
    const float* __restrict__ psw,
    float*       __restrict__ out)
{
    const unsigned tid = blockIdx.x * NTHREADS + threadIdx.x;

    for (unsigned g = tid; g < TOTAL_GROUPS; g += GRID_THREADS) {
        // table of this group (branchless; boundaries are table-major prefixes)
        const int t = (g >= 32768u) + (g >= 98304u) + (g >= 229376u)
                    + (g >= 491520u) + (g >= 524288u) + (g >= 589824u)
                    + (g >= 720896u);

        const int      s     = c_s[t];                 // log2(dim/4)
        const unsigned local = g - c_pref[t];
        const unsigned b     = local >> s;
        const unsigned cg    = local & ((1u << s) - 1u);
        const int      ld    = s + 2;                  // log2(dim)
        const unsigned wbase = c_woff[t] + (cg << 2);

        const unsigned ibase = ((unsigned)(t * BATCH) + b) << 5;  // *BAG_L
        const int4*   idx4 = (const int4*)(indices + ibase);
        const float4* pw4  = (const float4*)(psw + ibase);

        float4 acc = make_float4(0.f, 0.f, 0.f, 0.f);
#pragma unroll 2
        for (int j = 0; j < 8; ++j) {
            const int4   i4 = idx4[j];
            const float4 w4 = pw4[j];

            const float4 v0 = *(const float4*)(weights + (size_t)(wbase + ((unsigned)i4.x << ld)));
            const float4 v1 = *(const float4*)(weights + (size_t)(wbase + ((unsigned)i4.y << ld)));
            const float4 v2 = *(const float4*)(weights + (size_t)(wbase + ((unsigned)i4.z << ld)));
            const float4 v3 = *(const float4*)(weights + (size_t)(wbase + ((unsigned)i4.w << ld)));

            acc.x += v0.x * w4.x; acc.y += v0.y * w4.x;
            acc.z += v0.z * w4.x; acc.w += v0.w * w4.x;
            acc.x += v1.x * w4.y; acc.y += v1.y * w4.y;
            acc.z += v1.z * w4.y; acc.w += v1.w * w4.y;
            acc.x += v2.x * w4.z; acc.y += v2.y * w4.z;
            acc.z += v2.z * w4.z; acc.w += v2.w * w4.z;
            acc.x += v3.x * w4.w; acc.y += v3.y * w4.w;
            acc.z += v3.z * w4.w; acc.w += v3.w * w4.w;
        }

        ((float4*)out)[b * GROUPS_PER_ROW + c_cb[t] + cg] = acc;
    }
}

extern "C" void kernel_launch(void* const* d_in, const int* in_sizes, int n_in,
                              void* d_out, int out_size, void* d_ws, size_t ws_size,
                              hipStream_t stream) {
    const float* weights = (const float*)d_in[0];
    const int*   indices = (const int*)d_in[1];
    // d_in[2] = offsets (uniform stride L=32, unused)
    const float* psw     = (const float*)d_in[3];
    float*       out     = (float*)d_out;

    emb_bags_kernel<<<NBLOCKS, NTHREADS, 0, stream>>>(weights, indices, psw, out);
}

// Round 2
// 603.146 us; speedup vs baseline: 1.0132x; 1.0009x over previous
//
#include <hip/hip_runtime.h>

// MixedDimTableBatchedEmbeddingBags — table-phased persistent kernel, deep-ILP.
// 8 tables, 250k rows, dims {16,32,64,128,16,32,64,128}, B=8192, L=32.
// out[b, cb_t + 4*cg + d] = sum_l weights[woff_t + idx[t,b,l]*dim_t + 4*cg + d] * psw[t,b,l]
//
// R2 change: the bag loop is FULLY unrolled. All 16 idx/psw vector loads are
// issued before the 32 weight gathers, so each group exposes ONE idx-load
// latency instead of four, and the gather burst can keep ~12-16 lines in
// flight per wave (vs ~8 with unroll-2 + per-trip idx stalls). Accumulator is
// split (a0/a1) to shorten FMA dependency chains. VGPR capped at 128 via
// __launch_bounds__(256,4) -> exactly 4 blocks/CU resident (grid 1024).

#define BATCH    8192
#define GROUPS_PER_ROW 120                      // 480 floats / 4
#define TOTAL_GROUPS (BATCH * GROUPS_PER_ROW)   // 983040
#define NBLOCKS  1024
#define NTHREADS 256
#define GRID_THREADS (NBLOCKS * NTHREADS)       // 262144 -> 4 sweeps (3.75)

// per-table float4-group prefix:  G_t = B * dim_t/4
__constant__ unsigned c_pref[8] = {0u, 32768u, 98304u, 229376u,
                                   491520u, 524288u, 589824u, 720896u};
__constant__ int      c_s[8]    = {2, 3, 4, 5, 2, 3, 4, 5};   // log2(dim/4)
__constant__ int      c_cb[8]   = {0, 4, 12, 28, 60, 64, 72, 88};
__constant__ unsigned c_woff[8] = {0u, 4000000u, 12000000u, 28000000u,
                                   60000000u, 64000000u, 72000000u, 88000000u};

__global__ __launch_bounds__(NTHREADS, 4) void emb_bags_kernel(
    const float* __restrict__ weights,
    const int*   __restrict__ indices,
    const float* __restrict__ psw,
    float*       __restrict__ out)
{
    const unsigned tid = blockIdx.x * NTHREADS + threadIdx.x;

    for (unsigned g = tid; g < TOTAL_GROUPS; g += GRID_THREADS) {
        // table of this group (branchless; boundaries are table-major prefixes)
        const int t = (g >= 32768u) + (g >= 98304u) + (g >= 229376u)
                    + (g >= 491520u) + (g >= 524288u) + (g >= 589824u)
                    + (g >= 720896u);

        const int      s     = c_s[t];                 // log2(dim/4)
        const unsigned local = g - c_pref[t];
        const unsigned b     = local >> s;
        const unsigned cg    = local & ((1u << s) - 1u);
        const int      ld    = s + 2;                  // log2(dim)
        const float*   wp    = weights + c_woff[t] + (cg << 2);

        const unsigned ibase = ((unsigned)(t * BATCH) + b) << 5;  // *BAG_L
        const int4*   idx4 = (const int4*)(indices + ibase);
        const float4* pw4  = (const float4*)(psw + ibase);

        // Stage ALL bag metadata first: 8 int4 + 8 float4 = 16 independent
        // vector loads; first gather then waits on I[0] only.
        int4   I[8];
        float4 W[8];
#pragma unroll
        for (int j = 0; j < 8; ++j) { I[j] = idx4[j]; W[j] = pw4[j]; }

        float4 a0 = make_float4(0.f, 0.f, 0.f, 0.f);
        float4 a1 = make_float4(0.f, 0.f, 0.f, 0.f);

        // 32 independent gathers, fully unrolled — compiler schedules one
        // long vmcnt-pipelined burst.
#pragma unroll
        for (int j = 0; j < 8; ++j) {
            const float4 v0 = *(const float4*)(wp + ((size_t)((unsigned)I[j].x << ld)));
            const float4 v1 = *(const float4*)(wp + ((size_t)((unsigned)I[j].y << ld)));
            const float4 v2 = *(const float4*)(wp + ((size_t)((unsigned)I[j].z << ld)));
            const float4 v3 = *(const float4*)(wp + ((size_t)((unsigned)I[j].w << ld)));

            a0.x += v0.x * W[j].x; a0.y += v0.y * W[j].x;
            a0.z += v0.z * W[j].x; a0.w += v0.w * W[j].x;
            a1.x += v1.x * W[j].y; a1.y += v1.y * W[j].y;
            a1.z += v1.z * W[j].y; a1.w += v1.w * W[j].y;
            a0.x += v2.x * W[j].z; a0.y += v2.y * W[j].z;
            a0.z += v2.z * W[j].z; a0.w += v2.w * W[j].z;
            a1.x += v3.x * W[j].w; a1.y += v3.y * W[j].w;
            a1.z += v3.z * W[j].w; a1.w += v3.w * W[j].w;
        }

        float4 acc;
        acc.x = a0.x + a1.x; acc.y = a0.y + a1.y;
        acc.z = a0.z + a1.z; acc.w = a0.w + a1.w;

        ((float4*)out)[b * GROUPS_PER_ROW + c_cb[t] + cg] = acc;
    }
}

extern "C" void kernel_launch(void* const* d_in, const int* in_sizes, int n_in,
                              void* d_out, int out_size, void* d_ws, size_t ws_size,
                              hipStream_t stream) {
    const float* weights = (const float*)d_in[0];
    const int*   indices = (const int*)d_in[1];
    // d_in[2] = offsets (uniform stride L=32, unused)
    const float* psw     = (const float*)d_in[3];
    float*       out     = (float*)d_out;

    emb_bags_kernel<<<NBLOCKS, NTHREADS, 0, stream>>>(weights, indices, psw, out);
}